// Round 1
// baseline (1553.044 us; speedup 1.0000x reference)
//
#include <hip/hip_runtime.h>
#include <math.h>

#define NPIX 6272       // B*H*W = 2*56*56
#define LVAL 3136       // H*W
#define CIN 192         // d_inner
#define NST 16          // d_state
#define HW 56

__device__ __forceinline__ float softplusf(float v) {
    return (v > 20.0f) ? v : log1pf(expf(v));
}

// K1: xz = x @ W_in ; split into xm (first 192) and z (last 192)
__global__ __launch_bounds__(384) void k_inproj(
    const float* __restrict__ x, const float* __restrict__ W_in,
    float* __restrict__ xm, float* __restrict__ z)
{
    __shared__ float xs[8][96];
    const int p0 = blockIdx.x * 8;
    const int t = threadIdx.x;
    for (int idx = t; idx < 8 * 96; idx += 384)
        xs[idx / 96][idx % 96] = x[p0 * 96 + idx];
    __syncthreads();
    float acc[8] = {0.f,0.f,0.f,0.f,0.f,0.f,0.f,0.f};
    for (int k = 0; k < 96; ++k) {
        float w = W_in[k * 384 + t];
#pragma unroll
        for (int p = 0; p < 8; ++p) acc[p] = fmaf(xs[p][k], w, acc[p]);
    }
#pragma unroll
    for (int p = 0; p < 8; ++p) {
        int pix = p0 + p;
        if (t < 192) xm[pix * CIN + t] = acc[p];
        else         z[pix * CIN + (t - 192)] = acc[p];
    }
}

// K2: depthwise 3x3 conv, pad 1 (cross-correlation, NHWC / HWIO)
__global__ __launch_bounds__(256) void k_conv(
    const float* __restrict__ xm, const float* __restrict__ cw,
    const float* __restrict__ cb, float* __restrict__ xcv)
{
    int e = blockIdx.x * 256 + threadIdx.x;
    if (e >= NPIX * CIN) return;
    int c = e % CIN;
    int pix = e / CIN;
    int w = pix % HW;
    int rest = pix / HW;
    int h = rest % HW;
    int b = rest / HW;
    float acc = cb[c];
#pragma unroll
    for (int ky = 0; ky < 3; ++ky) {
        int hh = h + ky - 1;
        if (hh < 0 || hh >= HW) continue;
#pragma unroll
        for (int kx = 0; kx < 3; ++kx) {
            int ww = w + kx - 1;
            if (ww < 0 || ww >= HW) continue;
            acc = fmaf(xm[((b * HW + hh) * HW + ww) * CIN + c],
                       cw[(ky * 3 + kx) * CIN + c], acc);
        }
    }
    xcv[e] = acc;
}

// K3a: x_dbl = xcv @ W_xproj, split into dtr(6) / B(16) / C(16)
__global__ __launch_bounds__(256) void k_xproj(
    const float* __restrict__ xcv, const float* __restrict__ W_xproj,
    float* __restrict__ dtr, float* __restrict__ Bp, float* __restrict__ Cp)
{
    int idx = blockIdx.x * 256 + threadIdx.x;
    if (idx >= NPIX * 38) return;
    int j = idx % 38;
    int pix = idx / 38;
    const float* xr = xcv + pix * CIN;
    float s = 0.f;
    for (int k = 0; k < CIN; ++k) s = fmaf(xr[k], W_xproj[k * 38 + j], s);
    if (j < 6)       dtr[pix * 6 + j] = s;
    else if (j < 22) Bp[pix * NST + (j - 6)] = s;
    else             Cp[pix * NST + (j - 22)] = s;
}

// K3b: dt = softplus(dtr @ W_dt + b_dt)
__global__ __launch_bounds__(256) void k_dt(
    const float* __restrict__ dtr, const float* __restrict__ W_dt,
    const float* __restrict__ b_dt, float* __restrict__ dtp)
{
    int idx = blockIdx.x * 256 + threadIdx.x;
    if (idx >= NPIX * CIN) return;
    int c = idx % CIN;
    int pix = idx / CIN;
    float v = b_dt[c];
#pragma unroll
    for (int r = 0; r < 6; ++r) v = fmaf(dtr[pix * 6 + r], W_dt[r * CIN + c], v);
    dtp[idx] = softplusf(v);
}

// K4a: zero the y accumulator
__global__ __launch_bounds__(256) void k_zero(float* __restrict__ p)
{
    int idx = blockIdx.x * 256 + threadIdx.x;
    if (idx < NPIX * CIN) p[idx] = 0.f;
}

// K4b: selective scan. One wave per (g, 4-channel group).
// lane = cl*16 + n ; h in register; n-reduction via shfl_xor; atomicAdd into ysum.
__global__ __launch_bounds__(64) void k_scan(
    const float* __restrict__ xcv, const float* __restrict__ dtp,
    const float* __restrict__ Bp, const float* __restrict__ Cp,
    const float* __restrict__ A_log, const float* __restrict__ D_skip,
    float* __restrict__ ysum)
{
    const int g = blockIdx.y;          // 0..7  (g = d*2 + b)
    const int cg = blockIdx.x;         // 0..47
    const int t = threadIdx.x;
    const int n = t & 15;
    const int cl = t >> 4;
    const int c = cg * 4 + cl;
    const int d = g >> 1;
    const int b = g & 1;

    const float LOG2E = 1.4426950408889634f;
    const float a2 = -expf(A_log[c * NST + n]) * LOG2E;  // A * log2(e)
    const float Dc = D_skip[c];

    // pixel(l) = off + i*si + j*sj, where l = i*56 + j
    int si, sj, off;
    if (d == 0)      { si = HW;  sj = 1;   off = b * LVAL; }
    else if (d == 1) { si = HW;  sj = -1;  off = b * LVAL + (HW - 1); }
    else if (d == 2) { si = 1;   sj = HW;  off = b * LVAL; }
    else             { si = -1;  sj = HW;  off = b * LVAL + (HW - 1); }

    float h = 0.f;
    float* yo = ysum + (size_t)b * LVAL * CIN;

    // prefetch l = 0
    int pix = off;
    float dt_v = dtp[pix * CIN + c];
    float x_v  = xcv[pix * CIN + c];
    float B_v  = Bp[pix * NST + n];
    float C_v  = Cp[pix * NST + n];

    int l = 0;
    for (int i = 0; i < HW; ++i) {
        for (int j = 0; j < HW; ++j) {
            float dt_c = dt_v, x_c = x_v, B_c = B_v, C_c = C_v;
            // prefetch next step
            int jn = j + 1, in = i;
            if (jn == HW) { jn = 0; in = i + 1; }
            if (in < HW) {
                int pixn = off + in * si + jn * sj;
                dt_v = dtp[pixn * CIN + c];
                x_v  = xcv[pixn * CIN + c];
                B_v  = Bp[pixn * NST + n];
                C_v  = Cp[pixn * NST + n];
            }
            float dA = exp2f(dt_c * a2);
            h = fmaf(dA, h, dt_c * B_c * x_c);
            float yc = h * C_c;
            yc += __shfl_xor(yc, 1, 64);
            yc += __shfl_xor(yc, 2, 64);
            yc += __shfl_xor(yc, 4, 64);
            yc += __shfl_xor(yc, 8, 64);
            if (n == 0)
                atomicAdd(&yo[l * CIN + c], fmaf(Dc, x_c, yc));
            ++l;
        }
    }
}

// K5a: yv = silu(z) * ysum   (elementwise, same flat layout)
__global__ __launch_bounds__(256) void k_gate(
    const float* __restrict__ ysum, const float* __restrict__ z,
    float* __restrict__ yv)
{
    int idx = blockIdx.x * 256 + threadIdx.x;
    if (idx >= NPIX * CIN) return;
    float zz = z[idx];
    float sig = 1.f / (1.f + expf(-zz));
    yv[idx] = zz * sig * ysum[idx];
}

// K5b: out = yv @ W_out
__global__ __launch_bounds__(256) void k_outproj(
    const float* __restrict__ yv, const float* __restrict__ W_out,
    float* __restrict__ out)
{
    int idx = blockIdx.x * 256 + threadIdx.x;
    if (idx >= NPIX * 96) return;
    int j = idx % 96;
    int pix = idx / 96;
    const float* yr = yv + pix * CIN;
    float s = 0.f;
    for (int k = 0; k < CIN; ++k) s = fmaf(yr[k], W_out[k * 96 + j], s);
    out[idx] = s;
}

extern "C" void kernel_launch(void* const* d_in, const int* in_sizes, int n_in,
                              void* d_out, int out_size, void* d_ws, size_t ws_size,
                              hipStream_t stream) {
    const float* x      = (const float*)d_in[0];
    const float* W_in   = (const float*)d_in[1];
    const float* conv_w = (const float*)d_in[2];
    const float* conv_b = (const float*)d_in[3];
    const float* W_xproj= (const float*)d_in[4];
    const float* W_dt   = (const float*)d_in[5];
    const float* b_dt   = (const float*)d_in[6];
    const float* A_log  = (const float*)d_in[7];
    const float* D_skip = (const float*)d_in[8];
    const float* W_out  = (const float*)d_in[9];
    float* out = (float*)d_out;

    float* ws  = (float*)d_ws;
    float* xm  = ws;                    // [NPIX*CIN] ; later reused as ysum
    float* z   = xm  + NPIX * CIN;      // [NPIX*CIN]
    float* xcv = z   + NPIX * CIN;      // [NPIX*CIN] ; later reused as yv
    float* dtp = xcv + NPIX * CIN;      // [NPIX*CIN]
    float* dtr = dtp + NPIX * CIN;      // [NPIX*6]
    float* Bp  = dtr + NPIX * 6;        // [NPIX*NST]
    float* Cp  = Bp  + NPIX * NST;      // [NPIX*NST]
    // total: 4*1204224 + 37632 + 2*100352 = 5,055,424 floats ~= 20.2 MB

    k_inproj <<<NPIX / 8, 384, 0, stream>>>(x, W_in, xm, z);
    k_conv   <<<(NPIX * CIN) / 256, 256, 0, stream>>>(xm, conv_w, conv_b, xcv);
    k_xproj  <<<(NPIX * 38 + 255) / 256, 256, 0, stream>>>(xcv, W_xproj, dtr, Bp, Cp);
    k_dt     <<<(NPIX * CIN) / 256, 256, 0, stream>>>(dtr, W_dt, b_dt, dtp);
    k_zero   <<<(NPIX * CIN) / 256, 256, 0, stream>>>(xm);            // ysum = 0
    k_scan   <<<dim3(48, 8), 64, 0, stream>>>(xcv, dtp, Bp, Cp, A_log, D_skip, xm);
    k_gate   <<<(NPIX * CIN) / 256, 256, 0, stream>>>(xm, z, xcv);    // yv -> xcv
    k_outproj<<<(NPIX * 96) / 256, 256, 0, stream>>>(xcv, W_out, out);
}

// Round 2
// 319.344 us; speedup vs baseline: 4.8632x; 4.8632x over previous
//
#include <hip/hip_runtime.h>
#include <math.h>

#define NPIX 6272       // B*H*W = 2*56*56
#define LVAL 3136       // H*W
#define CIN 192         // d_inner
#define NST 16          // d_state
#define HW 56
#define NCHUNK 56       // one chunk per scan-row (L = 56*56)

__device__ __forceinline__ float softplusf(float v) {
    return (v > 20.0f) ? v : log1pf(expf(v));
}

// direction geometry: pixel(l) = off + i*si + j*sj, l = i*56 + j
__device__ __forceinline__ void dir_geom(int d, int b, int& si, int& sj, int& off) {
    if (d == 0)      { si = HW;  sj = 1;   off = b * LVAL; }
    else if (d == 1) { si = HW;  sj = -1;  off = b * LVAL + (HW - 1); }
    else if (d == 2) { si = 1;   sj = HW;  off = b * LVAL; }
    else             { si = -1;  sj = HW;  off = b * LVAL + (HW - 1); }
}

// K1: xz = x @ W_in ; split into xm (first 192) and z (last 192)
__global__ __launch_bounds__(384) void k_inproj(
    const float* __restrict__ x, const float* __restrict__ W_in,
    float* __restrict__ xm, float* __restrict__ z)
{
    __shared__ float xs[8][96];
    const int p0 = blockIdx.x * 8;
    const int t = threadIdx.x;
    for (int idx = t; idx < 8 * 96; idx += 384)
        xs[idx / 96][idx % 96] = x[p0 * 96 + idx];
    __syncthreads();
    float acc[8] = {0.f,0.f,0.f,0.f,0.f,0.f,0.f,0.f};
    for (int k = 0; k < 96; ++k) {
        float w = W_in[k * 384 + t];
#pragma unroll
        for (int p = 0; p < 8; ++p) acc[p] = fmaf(xs[p][k], w, acc[p]);
    }
#pragma unroll
    for (int p = 0; p < 8; ++p) {
        int pix = p0 + p;
        if (t < 192) xm[pix * CIN + t] = acc[p];
        else         z[pix * CIN + (t - 192)] = acc[p];
    }
}

// K2: depthwise 3x3 conv, pad 1
__global__ __launch_bounds__(256) void k_conv(
    const float* __restrict__ xm, const float* __restrict__ cw,
    const float* __restrict__ cb, float* __restrict__ xcv)
{
    int e = blockIdx.x * 256 + threadIdx.x;
    if (e >= NPIX * CIN) return;
    int c = e % CIN;
    int pix = e / CIN;
    int w = pix % HW;
    int rest = pix / HW;
    int h = rest % HW;
    int b = rest / HW;
    float acc = cb[c];
#pragma unroll
    for (int ky = 0; ky < 3; ++ky) {
        int hh = h + ky - 1;
        if (hh < 0 || hh >= HW) continue;
#pragma unroll
        for (int kx = 0; kx < 3; ++kx) {
            int ww = w + kx - 1;
            if (ww < 0 || ww >= HW) continue;
            acc = fmaf(xm[((b * HW + hh) * HW + ww) * CIN + c],
                       cw[(ky * 3 + kx) * CIN + c], acc);
        }
    }
    xcv[e] = acc;
}

// K3a: x_dbl = xcv @ W_xproj, split into dtr(6) / B(16) / C(16)
__global__ __launch_bounds__(256) void k_xproj(
    const float* __restrict__ xcv, const float* __restrict__ W_xproj,
    float* __restrict__ dtr, float* __restrict__ Bp, float* __restrict__ Cp)
{
    int idx = blockIdx.x * 256 + threadIdx.x;
    if (idx >= NPIX * 38) return;
    int j = idx % 38;
    int pix = idx / 38;
    const float* xr = xcv + pix * CIN;
    float s = 0.f;
    for (int k = 0; k < CIN; ++k) s = fmaf(xr[k], W_xproj[k * 38 + j], s);
    if (j < 6)       dtr[pix * 6 + j] = s;
    else if (j < 22) Bp[pix * NST + (j - 6)] = s;
    else             Cp[pix * NST + (j - 22)] = s;
}

// K3b: dt = softplus(dtr @ W_dt + b_dt)
__global__ __launch_bounds__(256) void k_dt(
    const float* __restrict__ dtr, const float* __restrict__ W_dt,
    const float* __restrict__ b_dt, float* __restrict__ dtp)
{
    int idx = blockIdx.x * 256 + threadIdx.x;
    if (idx >= NPIX * CIN) return;
    int c = idx % CIN;
    int pix = idx / CIN;
    float v = b_dt[c];
#pragma unroll
    for (int r = 0; r < 6; ++r) v = fmaf(dtr[pix * 6 + r], W_dt[r * CIN + c], v);
    dtp[idx] = softplusf(v);
}

// K4a: zero the y accumulator
__global__ __launch_bounds__(256) void k_zero(float* __restrict__ p)
{
    int idx = blockIdx.x * 256 + threadIdx.x;
    if (idx < NPIX * CIN) p[idx] = 0.f;
}

// K4b pass1: per-chunk (P = prod dA, q = local scan end). 4 waves/block,
// wave = (g, cg, chunk k). lane = cl*16 + n.
__global__ __launch_bounds__(256) void k_scan_p1(
    const float* __restrict__ xcv, const float* __restrict__ dtp,
    const float* __restrict__ Bp, const float* __restrict__ A_log,
    float* __restrict__ Pbuf, float* __restrict__ qbuf)
{
    const int wl = threadIdx.x >> 6;
    const int t  = threadIdx.x & 63;
    const int k  = blockIdx.z * 4 + wl;    // chunk 0..55
    const int g  = blockIdx.y;             // 0..7
    const int cg = blockIdx.x;             // 0..47
    const int n = t & 15, cl = t >> 4;
    const int c = cg * 4 + cl;
    const int d = g >> 1, b = g & 1;

    const float LOG2E = 1.4426950408889634f;
    const float a2 = -expf(A_log[c * NST + n]) * LOG2E;
    int si, sj, off;
    dir_geom(d, b, si, sj, off);
    const int base = off + k * si;

    float h = 0.f, P = 1.f;
    int pix = base;
    float dt_v = dtp[pix * CIN + c];
    float x_v  = xcv[pix * CIN + c];
    float B_v  = Bp[pix * NST + n];
    for (int j = 0; j < HW; ++j) {
        float dt_c = dt_v, x_c = x_v, B_c = B_v;
        int jn = (j + 1 < HW) ? j + 1 : j;
        int pixn = base + jn * sj;
        dt_v = dtp[pixn * CIN + c];
        x_v  = xcv[pixn * CIN + c];
        B_v  = Bp[pixn * NST + n];
        float dA = exp2f(dt_c * a2);
        h = fmaf(dA, h, dt_c * B_c * x_c);
        P *= dA;
    }
    int idx = ((k * 8 + g) * 48 + cg) * 64 + t;
    Pbuf[idx] = P;
    qbuf[idx] = h;
}

// K4c: sequential chunk combine; overwrites qbuf[k] with h_start of chunk k.
__global__ __launch_bounds__(64) void k_scan_fix(
    const float* __restrict__ Pbuf, float* __restrict__ qbuf)
{
    const int t = threadIdx.x;
    const int g = blockIdx.y, cg = blockIdx.x;
    float h = 0.f;
    for (int k = 0; k < NCHUNK; ++k) {
        int idx = ((k * 8 + g) * 48 + cg) * 64 + t;
        float Pk = Pbuf[idx], qk = qbuf[idx];
        qbuf[idx] = h;                 // h_start for chunk k
        h = fmaf(Pk, h, qk);
    }
}

// K4d pass2: rerun chunk from h_start, emit y (shfl-reduce over n, atomicAdd).
__global__ __launch_bounds__(256) void k_scan_p2(
    const float* __restrict__ xcv, const float* __restrict__ dtp,
    const float* __restrict__ Bp, const float* __restrict__ Cp,
    const float* __restrict__ A_log, const float* __restrict__ D_skip,
    const float* __restrict__ qbuf, float* __restrict__ ysum)
{
    const int wl = threadIdx.x >> 6;
    const int t  = threadIdx.x & 63;
    const int k  = blockIdx.z * 4 + wl;
    const int g  = blockIdx.y;
    const int cg = blockIdx.x;
    const int n = t & 15, cl = t >> 4;
    const int c = cg * 4 + cl;
    const int d = g >> 1, b = g & 1;

    const float LOG2E = 1.4426950408889634f;
    const float a2 = -expf(A_log[c * NST + n]) * LOG2E;
    const float Dc = D_skip[c];
    int si, sj, off;
    dir_geom(d, b, si, sj, off);
    const int base = off + k * si;

    float h = qbuf[((k * 8 + g) * 48 + cg) * 64 + t];
    float* yo = ysum + (size_t)b * LVAL * CIN + (size_t)(k * HW) * CIN;

    int pix = base;
    float dt_v = dtp[pix * CIN + c];
    float x_v  = xcv[pix * CIN + c];
    float B_v  = Bp[pix * NST + n];
    float C_v  = Cp[pix * NST + n];
    for (int j = 0; j < HW; ++j) {
        float dt_c = dt_v, x_c = x_v, B_c = B_v, C_c = C_v;
        int jn = (j + 1 < HW) ? j + 1 : j;
        int pixn = base + jn * sj;
        dt_v = dtp[pixn * CIN + c];
        x_v  = xcv[pixn * CIN + c];
        B_v  = Bp[pixn * NST + n];
        C_v  = Cp[pixn * NST + n];
        float dA = exp2f(dt_c * a2);
        h = fmaf(dA, h, dt_c * B_c * x_c);
        float yc = h * C_c;
        yc += __shfl_xor(yc, 1, 64);
        yc += __shfl_xor(yc, 2, 64);
        yc += __shfl_xor(yc, 4, 64);
        yc += __shfl_xor(yc, 8, 64);
        if (n == 0)
            atomicAdd(&yo[j * CIN + c], fmaf(Dc, x_c, yc));
    }
}

// K5a: yv = silu(z) * ysum
__global__ __launch_bounds__(256) void k_gate(
    const float* __restrict__ ysum, const float* __restrict__ z,
    float* __restrict__ yv)
{
    int idx = blockIdx.x * 256 + threadIdx.x;
    if (idx >= NPIX * CIN) return;
    float zz = z[idx];
    float sig = 1.f / (1.f + expf(-zz));
    yv[idx] = zz * sig * ysum[idx];
}

// K5b: out = yv @ W_out
__global__ __launch_bounds__(256) void k_outproj(
    const float* __restrict__ yv, const float* __restrict__ W_out,
    float* __restrict__ out)
{
    int idx = blockIdx.x * 256 + threadIdx.x;
    if (idx >= NPIX * 96) return;
    int j = idx % 96;
    int pix = idx / 96;
    const float* yr = yv + pix * CIN;
    float s = 0.f;
    for (int k = 0; k < CIN; ++k) s = fmaf(yr[k], W_out[k * 96 + j], s);
    out[idx] = s;
}

extern "C" void kernel_launch(void* const* d_in, const int* in_sizes, int n_in,
                              void* d_out, int out_size, void* d_ws, size_t ws_size,
                              hipStream_t stream) {
    const float* x      = (const float*)d_in[0];
    const float* W_in   = (const float*)d_in[1];
    const float* conv_w = (const float*)d_in[2];
    const float* conv_b = (const float*)d_in[3];
    const float* W_xproj= (const float*)d_in[4];
    const float* W_dt   = (const float*)d_in[5];
    const float* b_dt   = (const float*)d_in[6];
    const float* A_log  = (const float*)d_in[7];
    const float* D_skip = (const float*)d_in[8];
    const float* W_out  = (const float*)d_in[9];
    float* out = (float*)d_out;

    float* ws  = (float*)d_ws;
    float* xm  = ws;                    // [NPIX*CIN] ; later reused as ysum
    float* z   = xm  + NPIX * CIN;      // [NPIX*CIN]
    float* xcv = z   + NPIX * CIN;      // [NPIX*CIN] ; later reused as yv
    float* dtp = xcv + NPIX * CIN;      // [NPIX*CIN]
    float* dtr = dtp + NPIX * CIN;      // [NPIX*6]
    float* Bp  = dtr + NPIX * 6;        // [NPIX*NST]
    float* Cp  = Bp  + NPIX * NST;      // [NPIX*NST]
    float* Pbuf= Cp  + NPIX * NST;      // [56*8*48*64] = 1,376,256
    float* qbuf= Pbuf+ NCHUNK * 8 * 48 * 64; // same size
    // total ~ 7.81 M floats ~= 31.2 MB

    k_inproj  <<<NPIX / 8, 384, 0, stream>>>(x, W_in, xm, z);
    k_conv    <<<(NPIX * CIN) / 256, 256, 0, stream>>>(xm, conv_w, conv_b, xcv);
    k_xproj   <<<(NPIX * 38 + 255) / 256, 256, 0, stream>>>(xcv, W_xproj, dtr, Bp, Cp);
    k_dt      <<<(NPIX * CIN) / 256, 256, 0, stream>>>(dtr, W_dt, b_dt, dtp);
    k_zero    <<<(NPIX * CIN) / 256, 256, 0, stream>>>(xm);            // ysum = 0
    k_scan_p1 <<<dim3(48, 8, 14), 256, 0, stream>>>(xcv, dtp, Bp, A_log, Pbuf, qbuf);
    k_scan_fix<<<dim3(48, 8), 64, 0, stream>>>(Pbuf, qbuf);
    k_scan_p2 <<<dim3(48, 8, 14), 256, 0, stream>>>(xcv, dtp, Bp, Cp, A_log, D_skip, qbuf, xm);
    k_gate    <<<(NPIX * CIN) / 256, 256, 0, stream>>>(xm, z, xcv);    // yv -> xcv
    k_outproj <<<(NPIX * 96) / 256, 256, 0, stream>>>(xcv, W_out, out);
}

// Round 5
// 265.405 us; speedup vs baseline: 5.8516x; 1.2032x over previous
//
#include <hip/hip_runtime.h>
#include <math.h>

#define NPIX 6272       // B*H*W = 2*56*56
#define LVAL 3136       // H*W
#define CIN 192         // d_inner
#define NST 16          // d_state
#define HW 56
#define CHUNK 56        // steps per chunk = one full scan-row
#define NCH 56          // chunks per sequence

__device__ __forceinline__ float softplusf(float v) {
    return (v > 20.0f) ? v : log1pf(expf(v));
}

// direction geometry: pixel(l) = off + i*si + j*sj, l = i*56 + j
__device__ __forceinline__ void dir_geom(int d, int b, int& si, int& sj, int& off) {
    if (d == 0)      { si = HW;  sj = 1;   off = b * LVAL; }
    else if (d == 1) { si = HW;  sj = -1;  off = b * LVAL + (HW - 1); }
    else if (d == 2) { si = 1;   sj = HW;  off = b * LVAL; }
    else             { si = -1;  sj = HW;  off = b * LVAL + (HW - 1); }
}

// K1: xz = x @ W_in ; split into xm (first 192) and z (last 192)
__global__ __launch_bounds__(384) void k_inproj(
    const float* __restrict__ x, const float* __restrict__ W_in,
    float* __restrict__ xm, float* __restrict__ z)
{
    __shared__ float xs[8][96];
    const int p0 = blockIdx.x * 8;
    const int t = threadIdx.x;
    for (int idx = t; idx < 8 * 96; idx += 384)
        xs[idx / 96][idx % 96] = x[p0 * 96 + idx];
    __syncthreads();
    float acc[8] = {0.f,0.f,0.f,0.f,0.f,0.f,0.f,0.f};
    for (int k = 0; k < 96; ++k) {
        float w = W_in[k * 384 + t];
#pragma unroll
        for (int p = 0; p < 8; ++p) acc[p] = fmaf(xs[p][k], w, acc[p]);
    }
#pragma unroll
    for (int p = 0; p < 8; ++p) {
        int pix = p0 + p;
        if (t < 192) xm[pix * CIN + t] = acc[p];
        else         z[pix * CIN + (t - 192)] = acc[p];
    }
}

// K2: depthwise 3x3 conv, pad 1
__global__ __launch_bounds__(256) void k_conv(
    const float* __restrict__ xm, const float* __restrict__ cw,
    const float* __restrict__ cb, float* __restrict__ xcv)
{
    int e = blockIdx.x * 256 + threadIdx.x;
    if (e >= NPIX * CIN) return;
    int c = e % CIN;
    int pix = e / CIN;
    int w = pix % HW;
    int rest = pix / HW;
    int h = rest % HW;
    int b = rest / HW;
    float acc = cb[c];
#pragma unroll
    for (int ky = 0; ky < 3; ++ky) {
        int hh = h + ky - 1;
        if (hh < 0 || hh >= HW) continue;
#pragma unroll
        for (int kx = 0; kx < 3; ++kx) {
            int ww = w + kx - 1;
            if (ww < 0 || ww >= HW) continue;
            acc = fmaf(xm[((b * HW + hh) * HW + ww) * CIN + c],
                       cw[(ky * 3 + kx) * CIN + c], acc);
        }
    }
    xcv[e] = acc;
}

// K3a: x_dbl = xcv @ W_xproj, split into dtr(6) / B(16) / C(16)  [R2-proven]
__global__ __launch_bounds__(256) void k_xproj(
    const float* __restrict__ xcv, const float* __restrict__ W_xproj,
    float* __restrict__ dtr, float* __restrict__ Bp, float* __restrict__ Cp)
{
    int idx = blockIdx.x * 256 + threadIdx.x;
    if (idx >= NPIX * 38) return;
    int j = idx % 38;
    int pix = idx / 38;
    const float* xr = xcv + pix * CIN;
    float s = 0.f;
    for (int k = 0; k < CIN; ++k) s = fmaf(xr[k], W_xproj[k * 38 + j], s);
    if (j < 6)       dtr[pix * 6 + j] = s;
    else if (j < 22) Bp[pix * NST + (j - 6)] = s;
    else             Cp[pix * NST + (j - 22)] = s;
}

// K3b: dt = softplus(dtr @ W_dt + b_dt)
__global__ __launch_bounds__(256) void k_dt(
    const float* __restrict__ dtr, const float* __restrict__ W_dt,
    const float* __restrict__ b_dt, float* __restrict__ dtp)
{
    int idx = blockIdx.x * 256 + threadIdx.x;
    if (idx >= NPIX * CIN) return;
    int c = idx % CIN;
    int pix = idx / CIN;
    float v = b_dt[c];
#pragma unroll
    for (int r = 0; r < 6; ++r) v = fmaf(dtr[pix * 6 + r], W_dt[r * CIN + c], v);
    dtp[idx] = softplusf(v);
}

// K4a: zero the y accumulator
__global__ __launch_bounds__(256) void k_zero(float* __restrict__ p)
{
    int idx = blockIdx.x * 256 + threadIdx.x;
    if (idx < NPIX * CIN) p[idx] = 0.f;
}

// K4b pass1: lane = channel, 16 states in registers. Block = 192 thr = one (g, chunk).
__global__ __launch_bounds__(192) void k_scan_p1(
    const float* __restrict__ xcv, const float* __restrict__ dtp,
    const float* __restrict__ Bp, const float* __restrict__ A_log,
    float* __restrict__ Pbuf, float* __restrict__ qbuf)
{
    __shared__ __align__(16) float Bs[CHUNK * NST];
    const int g = blockIdx.y;          // 0..7
    const int k = blockIdx.x;          // 0..55 (row chunk)
    const int c = threadIdx.x;         // 0..191
    const int d = g >> 1, b = g & 1;
    int si, sj, off;
    dir_geom(d, b, si, sj, off);
    const int base = off + k * si;

    for (int e = c; e < CHUNK * NST; e += 192) {
        int jj = e >> 4, n = e & 15;
        Bs[e] = Bp[(base + jj * sj) * NST + n];
    }

    const float LOG2E = 1.4426950408889634f;
    float a2[NST];
    {
        const float4* Ar = (const float4*)(A_log + c * NST);
#pragma unroll
        for (int q = 0; q < 4; ++q) {
            float4 v = Ar[q];
            a2[q*4+0] = -expf(v.x) * LOG2E;
            a2[q*4+1] = -expf(v.y) * LOG2E;
            a2[q*4+2] = -expf(v.z) * LOG2E;
            a2[q*4+3] = -expf(v.w) * LOG2E;
        }
    }
    __syncthreads();

    float h[NST], P[NST];
#pragma unroll
    for (int n = 0; n < NST; ++n) { h[n] = 0.f; P[n] = 1.f; }

    float dt_v = dtp[base * CIN + c];
    float x_v  = xcv[base * CIN + c];
    for (int jj = 0; jj < CHUNK; ++jj) {
        float dt_c = dt_v, x_c = x_v;
        int jn = (jj + 1 < CHUNK) ? jj + 1 : jj;
        int pixn = base + jn * sj;
        dt_v = dtp[pixn * CIN + c];
        x_v  = xcv[pixn * CIN + c];
        float dtx = dt_c * x_c;
        float Bv[NST];
        {
            const float4* Brow = (const float4*)(Bs + jj * NST);
#pragma unroll
            for (int q = 0; q < 4; ++q) {
                float4 t = Brow[q];
                Bv[q*4+0]=t.x; Bv[q*4+1]=t.y; Bv[q*4+2]=t.z; Bv[q*4+3]=t.w;
            }
        }
#pragma unroll
        for (int n = 0; n < NST; ++n) {
            float dA = exp2f(dt_c * a2[n]);
            h[n] = fmaf(dA, h[n], dtx * Bv[n]);
            P[n] *= dA;
        }
    }
    float4* Pd = (float4*)(Pbuf + ((size_t)(k * 8 + g) * CIN + c) * NST);
    float4* qd = (float4*)(qbuf + ((size_t)(k * 8 + g) * CIN + c) * NST);
#pragma unroll
    for (int q = 0; q < 4; ++q) {
        Pd[q] = make_float4(P[q*4], P[q*4+1], P[q*4+2], P[q*4+3]);
        qd[q] = make_float4(h[q*4], h[q*4+1], h[q*4+2], h[q*4+3]);
    }
}

// K4c: sequential chunk combine; overwrites qbuf[k] with h_start of chunk k.
__global__ __launch_bounds__(256) void k_scan_fix(
    const float* __restrict__ Pbuf, float* __restrict__ qbuf)
{
    const int g = blockIdx.y;
    const int lo = blockIdx.x * 256 + threadIdx.x;   // 0..3071 = c*16+n
    const size_t stride = (size_t)8 * CIN * NST;     // 24576 per chunk
    size_t idx = (size_t)g * CIN * NST + lo;
    float h = 0.f;
    float P = Pbuf[idx], q = qbuf[idx];
    for (int k = 0; k < NCH; ++k) {
        float Pn = 0.f, qn = 0.f;
        if (k + 1 < NCH) { Pn = Pbuf[idx + stride]; qn = qbuf[idx + stride]; }
        qbuf[idx] = h;                 // h_start for chunk k
        h = fmaf(P, h, q);
        P = Pn; q = qn;
        idx += stride;
    }
}

// K4d pass2: rerun chunk from h_start; in-lane y accumulation.
// *** y accumulates at SEQUENCE position l = k*CHUNK + jj (reference sums
// *** scan outputs in sequence layout, NOT at the permuted spatial pixel).
__global__ __launch_bounds__(192) void k_scan_p2(
    const float* __restrict__ xcv, const float* __restrict__ dtp,
    const float* __restrict__ Bp, const float* __restrict__ Cp,
    const float* __restrict__ A_log, const float* __restrict__ D_skip,
    const float* __restrict__ qbuf, float* __restrict__ ysum)
{
    __shared__ __align__(16) float Bs[CHUNK * NST];
    __shared__ __align__(16) float Cs[CHUNK * NST];
    const int g = blockIdx.y;
    const int k = blockIdx.x;
    const int c = threadIdx.x;
    const int d = g >> 1, b = g & 1;
    int si, sj, off;
    dir_geom(d, b, si, sj, off);
    const int base = off + k * si;

    for (int e = c; e < CHUNK * NST; e += 192) {
        int jj = e >> 4, n = e & 15;
        int pa = (base + jj * sj) * NST + n;
        Bs[e] = Bp[pa];
        Cs[e] = Cp[pa];
    }

    const float LOG2E = 1.4426950408889634f;
    float a2[NST];
    {
        const float4* Ar = (const float4*)(A_log + c * NST);
#pragma unroll
        for (int q = 0; q < 4; ++q) {
            float4 v = Ar[q];
            a2[q*4+0] = -expf(v.x) * LOG2E;
            a2[q*4+1] = -expf(v.y) * LOG2E;
            a2[q*4+2] = -expf(v.z) * LOG2E;
            a2[q*4+3] = -expf(v.w) * LOG2E;
        }
    }
    const float Dc = D_skip[c];

    float h[NST];
    {
        const float4* qd = (const float4*)(qbuf + ((size_t)(k * 8 + g) * CIN + c) * NST);
#pragma unroll
        for (int q = 0; q < 4; ++q) {
            float4 v = qd[q];
            h[q*4+0]=v.x; h[q*4+1]=v.y; h[q*4+2]=v.z; h[q*4+3]=v.w;
        }
    }
    __syncthreads();

    // sequence-layout output slab for this (b, chunk): l = k*CHUNK + jj
    float* yo = ysum + ((size_t)b * LVAL + (size_t)k * CHUNK) * CIN;

    float dt_v = dtp[base * CIN + c];
    float x_v  = xcv[base * CIN + c];
    for (int jj = 0; jj < CHUNK; ++jj) {
        float dt_c = dt_v, x_c = x_v;
        int jn = (jj + 1 < CHUNK) ? jj + 1 : jj;
        int pixn = base + jn * sj;
        dt_v = dtp[pixn * CIN + c];
        x_v  = xcv[pixn * CIN + c];
        float dtx = dt_c * x_c;
        float Bv[NST], Cv[NST];
        {
            const float4* Brow = (const float4*)(Bs + jj * NST);
            const float4* Crow = (const float4*)(Cs + jj * NST);
#pragma unroll
            for (int q = 0; q < 4; ++q) {
                float4 t = Brow[q], u = Crow[q];
                Bv[q*4+0]=t.x; Bv[q*4+1]=t.y; Bv[q*4+2]=t.z; Bv[q*4+3]=t.w;
                Cv[q*4+0]=u.x; Cv[q*4+1]=u.y; Cv[q*4+2]=u.z; Cv[q*4+3]=u.w;
            }
        }
        float yc0 = Dc * x_c, yc1 = 0.f;
#pragma unroll
        for (int n = 0; n < NST; n += 2) {
            float dA0 = exp2f(dt_c * a2[n]);
            float dA1 = exp2f(dt_c * a2[n+1]);
            h[n]   = fmaf(dA0, h[n],   dtx * Bv[n]);
            h[n+1] = fmaf(dA1, h[n+1], dtx * Bv[n+1]);
            yc0 = fmaf(h[n],   Cv[n],   yc0);
            yc1 = fmaf(h[n+1], Cv[n+1], yc1);
        }
        atomicAdd(&yo[jj * CIN + c], yc0 + yc1);
    }
}

// K5a: yv = silu(z) * ysum
__global__ __launch_bounds__(256) void k_gate(
    const float* __restrict__ ysum, const float* __restrict__ z,
    float* __restrict__ yv)
{
    int idx = blockIdx.x * 256 + threadIdx.x;
    if (idx >= NPIX * CIN) return;
    float zz = z[idx];
    float sig = 1.f / (1.f + expf(-zz));
    yv[idx] = zz * sig * ysum[idx];
}

// K5b: out = yv @ W_out  [R2-proven]
__global__ __launch_bounds__(256) void k_outproj(
    const float* __restrict__ yv, const float* __restrict__ W_out,
    float* __restrict__ out)
{
    int idx = blockIdx.x * 256 + threadIdx.x;
    if (idx >= NPIX * 96) return;
    int j = idx % 96;
    int pix = idx / 96;
    const float* yr = yv + pix * CIN;
    float s = 0.f;
    for (int k = 0; k < CIN; ++k) s = fmaf(yr[k], W_out[k * 96 + j], s);
    out[idx] = s;
}

extern "C" void kernel_launch(void* const* d_in, const int* in_sizes, int n_in,
                              void* d_out, int out_size, void* d_ws, size_t ws_size,
                              hipStream_t stream) {
    const float* x      = (const float*)d_in[0];
    const float* W_in   = (const float*)d_in[1];
    const float* conv_w = (const float*)d_in[2];
    const float* conv_b = (const float*)d_in[3];
    const float* W_xproj= (const float*)d_in[4];
    const float* W_dt   = (const float*)d_in[5];
    const float* b_dt   = (const float*)d_in[6];
    const float* A_log  = (const float*)d_in[7];
    const float* D_skip = (const float*)d_in[8];
    const float* W_out  = (const float*)d_in[9];
    float* out = (float*)d_out;

    float* ws  = (float*)d_ws;
    float* xm  = ws;                        // [NPIX*CIN] ; reused as ysum
    float* z   = xm  + NPIX * CIN;          // [NPIX*CIN]
    float* xcv = z   + NPIX * CIN;          // [NPIX*CIN] ; reused as yv
    float* dtp = xcv + NPIX * CIN;          // [NPIX*CIN]
    float* dtr = dtp + NPIX * CIN;          // [NPIX*6]
    float* Bp  = dtr + NPIX * 6;            // [NPIX*NST]
    float* Cp  = Bp  + NPIX * NST;          // [NPIX*NST]
    float* Pbuf= Cp  + NPIX * NST;          // [NCH*8*CIN*NST] = 1,376,256
    float* qbuf= Pbuf + (size_t)NCH * 8 * CIN * NST;
    // total 7,807,744 floats = 31.2 MB (identical to passing R2 footprint)

    k_inproj  <<<NPIX / 8, 384, 0, stream>>>(x, W_in, xm, z);
    k_conv    <<<(NPIX * CIN) / 256, 256, 0, stream>>>(xm, conv_w, conv_b, xcv);
    k_xproj   <<<(NPIX * 38 + 255) / 256, 256, 0, stream>>>(xcv, W_xproj, dtr, Bp, Cp);
    k_dt      <<<(NPIX * CIN) / 256, 256, 0, stream>>>(dtr, W_dt, b_dt, dtp);
    k_zero    <<<(NPIX * CIN) / 256, 256, 0, stream>>>(xm);            // ysum = 0
    k_scan_p1 <<<dim3(NCH, 8), 192, 0, stream>>>(xcv, dtp, Bp, A_log, Pbuf, qbuf);
    k_scan_fix<<<dim3(12, 8), 256, 0, stream>>>(Pbuf, qbuf);
    k_scan_p2 <<<dim3(NCH, 8), 192, 0, stream>>>(xcv, dtp, Bp, Cp, A_log, D_skip, qbuf, xm);
    k_gate    <<<(NPIX * CIN) / 256, 256, 0, stream>>>(xm, z, xcv);    // yv -> xcv
    k_outproj <<<(NPIX * 96) / 256, 256, 0, stream>>>(xcv, W_out, out);
}

// Round 6
// 248.259 us; speedup vs baseline: 6.2557x; 1.0691x over previous
//
#include <hip/hip_runtime.h>
#include <math.h>

#define NPIX 6272       // B*H*W = 2*56*56
#define LVAL 3136       // H*W
#define CIN 192         // d_inner
#define NST 16          // d_state
#define HW 56

__device__ __forceinline__ float softplusf(float v) {
    return (v > 20.0f) ? v : log1pf(expf(v));
}

// direction geometry: pixel(l) = off + i*si + j*sj, l = i*56 + j
__device__ __forceinline__ void dir_geom(int d, int b, int& si, int& sj, int& off) {
    if (d == 0)      { si = HW;  sj = 1;   off = b * LVAL; }
    else if (d == 1) { si = HW;  sj = -1;  off = b * LVAL + (HW - 1); }
    else if (d == 2) { si = 1;   sj = HW;  off = b * LVAL; }
    else             { si = -1;  sj = HW;  off = b * LVAL + (HW - 1); }
}

// K1: xz = x @ W_in ; split into xm (first 192) and z (last 192)
// LDS layout xs[k][p]: inner loop reads 8 pixels via 2 broadcast ds_read_b128.
__global__ __launch_bounds__(384) void k_inproj(
    const float* __restrict__ x, const float* __restrict__ W_in,
    float* __restrict__ xm, float* __restrict__ z)
{
    __shared__ __align__(16) float xs[96][8];
    const int p0 = blockIdx.x * 8;
    const int t = threadIdx.x;
    for (int idx = t; idx < 8 * 96; idx += 384) {
        int p = idx / 96, kk = idx % 96;
        xs[kk][p] = x[p0 * 96 + idx];
    }
    __syncthreads();
    float acc[8] = {0.f,0.f,0.f,0.f,0.f,0.f,0.f,0.f};
    for (int k = 0; k < 96; ++k) {
        float w = W_in[k * 384 + t];
        float4 x0 = *(const float4*)&xs[k][0];
        float4 x1 = *(const float4*)&xs[k][4];
        acc[0] = fmaf(x0.x, w, acc[0]); acc[1] = fmaf(x0.y, w, acc[1]);
        acc[2] = fmaf(x0.z, w, acc[2]); acc[3] = fmaf(x0.w, w, acc[3]);
        acc[4] = fmaf(x1.x, w, acc[4]); acc[5] = fmaf(x1.y, w, acc[5]);
        acc[6] = fmaf(x1.z, w, acc[6]); acc[7] = fmaf(x1.w, w, acc[7]);
    }
#pragma unroll
    for (int p = 0; p < 8; ++p) {
        int pix = p0 + p;
        if (t < 192) xm[pix * CIN + t] = acc[p];
        else         z[pix * CIN + (t - 192)] = acc[p];
    }
}

// K2: depthwise 3x3 conv, pad 1
__global__ __launch_bounds__(256) void k_conv(
    const float* __restrict__ xm, const float* __restrict__ cw,
    const float* __restrict__ cb, float* __restrict__ xcv)
{
    int e = blockIdx.x * 256 + threadIdx.x;
    if (e >= NPIX * CIN) return;
    int c = e % CIN;
    int pix = e / CIN;
    int w = pix % HW;
    int rest = pix / HW;
    int h = rest % HW;
    int b = rest / HW;
    float acc = cb[c];
#pragma unroll
    for (int ky = 0; ky < 3; ++ky) {
        int hh = h + ky - 1;
        if (hh < 0 || hh >= HW) continue;
#pragma unroll
        for (int kx = 0; kx < 3; ++kx) {
            int ww = w + kx - 1;
            if (ww < 0 || ww >= HW) continue;
            acc = fmaf(xm[((b * HW + hh) * HW + ww) * CIN + c],
                       cw[(ky * 3 + kx) * CIN + c], acc);
        }
    }
    xcv[e] = acc;
}

// K3a: x_dbl = xcv @ W_xproj, split into dtr(6) / B(16) / C(16)
__global__ __launch_bounds__(256) void k_xproj(
    const float* __restrict__ xcv, const float* __restrict__ W_xproj,
    float* __restrict__ dtr, float* __restrict__ Bp, float* __restrict__ Cp)
{
    int idx = blockIdx.x * 256 + threadIdx.x;
    if (idx >= NPIX * 38) return;
    int j = idx % 38;
    int pix = idx / 38;
    const float* xr = xcv + pix * CIN;
    float s = 0.f;
    for (int k = 0; k < CIN; ++k) s = fmaf(xr[k], W_xproj[k * 38 + j], s);
    if (j < 6)       dtr[pix * 6 + j] = s;
    else if (j < 22) Bp[pix * NST + (j - 6)] = s;
    else             Cp[pix * NST + (j - 22)] = s;
}

// K3b: dt = softplus(dtr @ W_dt + b_dt)
__global__ __launch_bounds__(256) void k_dt(
    const float* __restrict__ dtr, const float* __restrict__ W_dt,
    const float* __restrict__ b_dt, float* __restrict__ dtp)
{
    int idx = blockIdx.x * 256 + threadIdx.x;
    if (idx >= NPIX * CIN) return;
    int c = idx % CIN;
    int pix = idx / CIN;
    float v = b_dt[c];
#pragma unroll
    for (int r = 0; r < 6; ++r) v = fmaf(dtr[pix * 6 + r], W_dt[r * CIN + c], v);
    dtp[idx] = softplusf(v);
}

// K4a: zero the y accumulator
__global__ __launch_bounds__(256) void k_zero(float* __restrict__ p)
{
    int idx = blockIdx.x * 256 + threadIdx.x;
    if (idx < NPIX * CIN) p[idx] = 0.f;
}

// K4b pass1 (templated on CHUNK): lane = channel, 16 states in registers.
template<int CHUNK>
__global__ __launch_bounds__(192) void k_scan_p1(
    const float* __restrict__ xcv, const float* __restrict__ dtp,
    const float* __restrict__ Bp, const float* __restrict__ A_log,
    float* __restrict__ Pbuf, float* __restrict__ qbuf)
{
    constexpr int CPR = HW / CHUNK;    // chunks per row
    __shared__ __align__(16) float Bs[CHUNK * NST];
    const int g = blockIdx.y;          // 0..7
    const int k = blockIdx.x;          // chunk id
    const int c = threadIdx.x;         // 0..191
    const int d = g >> 1, b = g & 1;
    int si, sj, off;
    dir_geom(d, b, si, sj, off);
    const int base = off + (k / CPR) * si + ((k % CPR) * CHUNK) * sj;

    for (int e = c; e < CHUNK * NST; e += 192) {
        int jj = e >> 4, n = e & 15;
        Bs[e] = Bp[(base + jj * sj) * NST + n];
    }

    const float LOG2E = 1.4426950408889634f;
    float a2[NST];
    {
        const float4* Ar = (const float4*)(A_log + c * NST);
#pragma unroll
        for (int q = 0; q < 4; ++q) {
            float4 v = Ar[q];
            a2[q*4+0] = -expf(v.x) * LOG2E;
            a2[q*4+1] = -expf(v.y) * LOG2E;
            a2[q*4+2] = -expf(v.z) * LOG2E;
            a2[q*4+3] = -expf(v.w) * LOG2E;
        }
    }
    __syncthreads();

    float h[NST], P[NST];
#pragma unroll
    for (int n = 0; n < NST; ++n) { h[n] = 0.f; P[n] = 1.f; }

    float dt_v = dtp[base * CIN + c];
    float x_v  = xcv[base * CIN + c];
    for (int jj = 0; jj < CHUNK; ++jj) {
        float dt_c = dt_v, x_c = x_v;
        int jn = (jj + 1 < CHUNK) ? jj + 1 : jj;
        int pixn = base + jn * sj;
        dt_v = dtp[pixn * CIN + c];
        x_v  = xcv[pixn * CIN + c];
        float dtx = dt_c * x_c;
        float Bv[NST];
        {
            const float4* Brow = (const float4*)(Bs + jj * NST);
#pragma unroll
            for (int q = 0; q < 4; ++q) {
                float4 t = Brow[q];
                Bv[q*4+0]=t.x; Bv[q*4+1]=t.y; Bv[q*4+2]=t.z; Bv[q*4+3]=t.w;
            }
        }
#pragma unroll
        for (int n = 0; n < NST; ++n) {
            float dA = exp2f(dt_c * a2[n]);
            h[n] = fmaf(dA, h[n], dtx * Bv[n]);
            P[n] *= dA;
        }
    }
    float4* Pd = (float4*)(Pbuf + ((size_t)(k * 8 + g) * CIN + c) * NST);
    float4* qd = (float4*)(qbuf + ((size_t)(k * 8 + g) * CIN + c) * NST);
#pragma unroll
    for (int q = 0; q < 4; ++q) {
        Pd[q] = make_float4(P[q*4], P[q*4+1], P[q*4+2], P[q*4+3]);
        qd[q] = make_float4(h[q*4], h[q*4+1], h[q*4+2], h[q*4+3]);
    }
}

// K4c: sequential chunk combine, 8-deep load pipeline; overwrites qbuf[k]
// with h_start of chunk k. nch is runtime (divisible by 8 for all CHUNK).
__global__ __launch_bounds__(256) void k_scan_fix(
    const float* __restrict__ Pbuf, float* __restrict__ qbuf, int nch)
{
    const int g = blockIdx.y;
    const int lo = blockIdx.x * 256 + threadIdx.x;   // 0..3071 = c*16+n
    const size_t stride = (size_t)8 * CIN * NST;     // 24576 per chunk
    size_t idx  = (size_t)g * CIN * NST + lo;
    size_t pidx = idx;
    float Pr[8], qr[8];
#pragma unroll
    for (int i = 0; i < 8; ++i) { Pr[i] = Pbuf[pidx]; qr[i] = qbuf[pidx]; pidx += stride; }
    float h = 0.f;
    for (int k = 0; k < nch; k += 8) {
        float Pn[8], qn[8];
        if (k + 8 < nch) {
#pragma unroll
            for (int i = 0; i < 8; ++i) {
                Pn[i] = Pbuf[pidx + (size_t)i * stride];
                qn[i] = qbuf[pidx + (size_t)i * stride];
            }
        } else {
#pragma unroll
            for (int i = 0; i < 8; ++i) { Pn[i] = 0.f; qn[i] = 0.f; }
        }
#pragma unroll
        for (int i = 0; i < 8; ++i) {
            qbuf[idx] = h;                 // h_start for chunk k+i
            h = fmaf(Pr[i], h, qr[i]);
            idx += stride;
        }
#pragma unroll
        for (int i = 0; i < 8; ++i) { Pr[i] = Pn[i]; qr[i] = qn[i]; }
        pidx += (size_t)8 * stride;
    }
}

// K4d pass2 (templated): rerun chunk from h_start; y accumulates at SEQUENCE
// position l = k*CHUNK + jj (reference sums scan outputs in sequence layout).
template<int CHUNK>
__global__ __launch_bounds__(192) void k_scan_p2(
    const float* __restrict__ xcv, const float* __restrict__ dtp,
    const float* __restrict__ Bp, const float* __restrict__ Cp,
    const float* __restrict__ A_log, const float* __restrict__ D_skip,
    const float* __restrict__ qbuf, float* __restrict__ ysum)
{
    constexpr int CPR = HW / CHUNK;
    __shared__ __align__(16) float Bs[CHUNK * NST];
    __shared__ __align__(16) float Cs[CHUNK * NST];
    const int g = blockIdx.y;
    const int k = blockIdx.x;
    const int c = threadIdx.x;
    const int d = g >> 1, b = g & 1;
    int si, sj, off;
    dir_geom(d, b, si, sj, off);
    const int base = off + (k / CPR) * si + ((k % CPR) * CHUNK) * sj;

    for (int e = c; e < CHUNK * NST; e += 192) {
        int jj = e >> 4, n = e & 15;
        int pa = (base + jj * sj) * NST + n;
        Bs[e] = Bp[pa];
        Cs[e] = Cp[pa];
    }

    const float LOG2E = 1.4426950408889634f;
    float a2[NST];
    {
        const float4* Ar = (const float4*)(A_log + c * NST);
#pragma unroll
        for (int q = 0; q < 4; ++q) {
            float4 v = Ar[q];
            a2[q*4+0] = -expf(v.x) * LOG2E;
            a2[q*4+1] = -expf(v.y) * LOG2E;
            a2[q*4+2] = -expf(v.z) * LOG2E;
            a2[q*4+3] = -expf(v.w) * LOG2E;
        }
    }
    const float Dc = D_skip[c];

    float h[NST];
    {
        const float4* qd = (const float4*)(qbuf + ((size_t)(k * 8 + g) * CIN + c) * NST);
#pragma unroll
        for (int q = 0; q < 4; ++q) {
            float4 v = qd[q];
            h[q*4+0]=v.x; h[q*4+1]=v.y; h[q*4+2]=v.z; h[q*4+3]=v.w;
        }
    }
    __syncthreads();

    float* yo = ysum + ((size_t)b * LVAL + (size_t)k * CHUNK) * CIN;

    float dt_v = dtp[base * CIN + c];
    float x_v  = xcv[base * CIN + c];
    for (int jj = 0; jj < CHUNK; ++jj) {
        float dt_c = dt_v, x_c = x_v;
        int jn = (jj + 1 < CHUNK) ? jj + 1 : jj;
        int pixn = base + jn * sj;
        dt_v = dtp[pixn * CIN + c];
        x_v  = xcv[pixn * CIN + c];
        float dtx = dt_c * x_c;
        float Bv[NST], Cv[NST];
        {
            const float4* Brow = (const float4*)(Bs + jj * NST);
            const float4* Crow = (const float4*)(Cs + jj * NST);
#pragma unroll
            for (int q = 0; q < 4; ++q) {
                float4 t = Brow[q], u = Crow[q];
                Bv[q*4+0]=t.x; Bv[q*4+1]=t.y; Bv[q*4+2]=t.z; Bv[q*4+3]=t.w;
                Cv[q*4+0]=u.x; Cv[q*4+1]=u.y; Cv[q*4+2]=u.z; Cv[q*4+3]=u.w;
            }
        }
        float yc0 = Dc * x_c, yc1 = 0.f;
#pragma unroll
        for (int n = 0; n < NST; n += 2) {
            float dA0 = exp2f(dt_c * a2[n]);
            float dA1 = exp2f(dt_c * a2[n+1]);
            h[n]   = fmaf(dA0, h[n],   dtx * Bv[n]);
            h[n+1] = fmaf(dA1, h[n+1], dtx * Bv[n+1]);
            yc0 = fmaf(h[n],   Cv[n],   yc0);
            yc1 = fmaf(h[n+1], Cv[n+1], yc1);
        }
        atomicAdd(&yo[jj * CIN + c], yc0 + yc1);
    }
}

// K5a: yv = silu(z) * ysum
__global__ __launch_bounds__(256) void k_gate(
    const float* __restrict__ ysum, const float* __restrict__ z,
    float* __restrict__ yv)
{
    int idx = blockIdx.x * 256 + threadIdx.x;
    if (idx >= NPIX * CIN) return;
    float zz = z[idx];
    float sig = 1.f / (1.f + expf(-zz));
    yv[idx] = zz * sig * ysum[idx];
}

// K5b: out = yv @ W_out
__global__ __launch_bounds__(256) void k_outproj(
    const float* __restrict__ yv, const float* __restrict__ W_out,
    float* __restrict__ out)
{
    int idx = blockIdx.x * 256 + threadIdx.x;
    if (idx >= NPIX * 96) return;
    int j = idx % 96;
    int pix = idx / 96;
    const float* yr = yv + pix * CIN;
    float s = 0.f;
    for (int k = 0; k < CIN; ++k) s = fmaf(yr[k], W_out[k * 96 + j], s);
    out[idx] = s;
}

template<int CHUNK>
static void launch_scan(const float* xcv, const float* dtp, const float* Bp,
                        const float* Cp, const float* A_log, const float* D_skip,
                        float* Pbuf, float* qbuf, float* ysum, hipStream_t stream)
{
    const int nch = LVAL / CHUNK;
    k_scan_p1<CHUNK><<<dim3(nch, 8), 192, 0, stream>>>(xcv, dtp, Bp, A_log, Pbuf, qbuf);
    k_scan_fix<<<dim3(12, 8), 256, 0, stream>>>(Pbuf, qbuf, nch);
    k_scan_p2<CHUNK><<<dim3(nch, 8), 192, 0, stream>>>(xcv, dtp, Bp, Cp, A_log, D_skip, qbuf, ysum);
}

extern "C" void kernel_launch(void* const* d_in, const int* in_sizes, int n_in,
                              void* d_out, int out_size, void* d_ws, size_t ws_size,
                              hipStream_t stream) {
    const float* x      = (const float*)d_in[0];
    const float* W_in   = (const float*)d_in[1];
    const float* conv_w = (const float*)d_in[2];
    const float* conv_b = (const float*)d_in[3];
    const float* W_xproj= (const float*)d_in[4];
    const float* W_dt   = (const float*)d_in[5];
    const float* b_dt   = (const float*)d_in[6];
    const float* A_log  = (const float*)d_in[7];
    const float* D_skip = (const float*)d_in[8];
    const float* W_out  = (const float*)d_in[9];
    float* out = (float*)d_out;

    float* ws  = (float*)d_ws;
    float* xm  = ws;                        // [NPIX*CIN] ; reused as ysum
    float* z   = xm  + NPIX * CIN;          // [NPIX*CIN]
    float* xcv = z   + NPIX * CIN;          // [NPIX*CIN] ; reused as yv
    float* dtp = xcv + NPIX * CIN;          // [NPIX*CIN]
    float* dtr = dtp + NPIX * CIN;          // [NPIX*6]
    float* Bp  = dtr + NPIX * 6;            // [NPIX*NST]
    float* Cp  = Bp  + NPIX * NST;          // [NPIX*NST]
    float* Pbuf= Cp  + NPIX * NST;          // [nch*8*CIN*NST]
    // base = 5,055,232 floats; carry bufs = 2*nch*24576 floats

    const size_t base_fl = 5055232;
    const size_t ws_fl = ws_size / 4;
    // pick smallest CHUNK (most parallelism) whose carry buffers fit
    int chunk;
    if      (ws_fl >= base_fl + (size_t)2 * 224 * 24576) chunk = 14;  // 64.3 MB
    else if (ws_fl >= base_fl + (size_t)2 * 112 * 24576) chunk = 28;  // 42.2 MB
    else                                                 chunk = 56;  // 31.2 MB
    float* qbuf = Pbuf + (size_t)(LVAL / chunk) * 8 * CIN * NST;

    k_inproj  <<<NPIX / 8, 384, 0, stream>>>(x, W_in, xm, z);
    k_conv    <<<(NPIX * CIN) / 256, 256, 0, stream>>>(xm, conv_w, conv_b, xcv);
    k_xproj   <<<(NPIX * 38 + 255) / 256, 256, 0, stream>>>(xcv, W_xproj, dtr, Bp, Cp);
    k_dt      <<<(NPIX * CIN) / 256, 256, 0, stream>>>(dtr, W_dt, b_dt, dtp);
    k_zero    <<<(NPIX * CIN) / 256, 256, 0, stream>>>(xm);            // ysum = 0
    if      (chunk == 14) launch_scan<14>(xcv, dtp, Bp, Cp, A_log, D_skip, Pbuf, qbuf, xm, stream);
    else if (chunk == 28) launch_scan<28>(xcv, dtp, Bp, Cp, A_log, D_skip, Pbuf, qbuf, xm, stream);
    else                  launch_scan<56>(xcv, dtp, Bp, Cp, A_log, D_skip, Pbuf, qbuf, xm, stream);
    k_gate    <<<(NPIX * CIN) / 256, 256, 0, stream>>>(xm, z, xcv);    // yv -> xcv
    k_outproj <<<(NPIX * 96) / 256, 256, 0, stream>>>(xcv, W_out, out);
}

// Round 7
// 228.948 us; speedup vs baseline: 6.7834x; 1.0843x over previous
//
#include <hip/hip_runtime.h>
#include <math.h>

#define NPIX 6272       // B*H*W = 2*56*56
#define LVAL 3136       // H*W
#define CIN 192         // d_inner
#define NST 16          // d_state
#define HW 56

__device__ __forceinline__ float softplusf(float v) {
    return (v > 20.0f) ? v : log1pf(expf(v));
}

// direction geometry: pixel(l) = off + i*si + j*sj, l = i*56 + j
__device__ __forceinline__ void dir_geom(int d, int b, int& si, int& sj, int& off) {
    if (d == 0)      { si = HW;  sj = 1;   off = b * LVAL; }
    else if (d == 1) { si = HW;  sj = -1;  off = b * LVAL + (HW - 1); }
    else if (d == 2) { si = 1;   sj = HW;  off = b * LVAL; }
    else             { si = -1;  sj = HW;  off = b * LVAL + (HW - 1); }
}

// K1: xz = x @ W_in ; 16 pixels/block, LDS-broadcast x, acc[16]/thread.
__global__ __launch_bounds__(384) void k_inproj(
    const float* __restrict__ x, const float* __restrict__ W_in,
    float* __restrict__ xm, float* __restrict__ z)
{
    __shared__ __align__(16) float xs[96][20];   // pad 20 keeps [k][4q] 16B-aligned
    const int p0 = blockIdx.x * 16;
    const int t = threadIdx.x;
    for (int e = t; e < 16 * 96; e += 384) {
        int p = e / 96, kk = e % 96;
        xs[kk][p] = x[p0 * 96 + e];
    }
    __syncthreads();
    float acc[16];
#pragma unroll
    for (int p = 0; p < 16; ++p) acc[p] = 0.f;
    for (int k = 0; k < 96; ++k) {
        float w = W_in[k * 384 + t];
        float4 x0 = *(const float4*)&xs[k][0];
        float4 x1 = *(const float4*)&xs[k][4];
        float4 x2 = *(const float4*)&xs[k][8];
        float4 x3 = *(const float4*)&xs[k][12];
        acc[0]  = fmaf(x0.x, w, acc[0]);  acc[1]  = fmaf(x0.y, w, acc[1]);
        acc[2]  = fmaf(x0.z, w, acc[2]);  acc[3]  = fmaf(x0.w, w, acc[3]);
        acc[4]  = fmaf(x1.x, w, acc[4]);  acc[5]  = fmaf(x1.y, w, acc[5]);
        acc[6]  = fmaf(x1.z, w, acc[6]);  acc[7]  = fmaf(x1.w, w, acc[7]);
        acc[8]  = fmaf(x2.x, w, acc[8]);  acc[9]  = fmaf(x2.y, w, acc[9]);
        acc[10] = fmaf(x2.z, w, acc[10]); acc[11] = fmaf(x2.w, w, acc[11]);
        acc[12] = fmaf(x3.x, w, acc[12]); acc[13] = fmaf(x3.y, w, acc[13]);
        acc[14] = fmaf(x3.z, w, acc[14]); acc[15] = fmaf(x3.w, w, acc[15]);
    }
#pragma unroll
    for (int p = 0; p < 16; ++p) {
        int pix = p0 + p;
        if (t < 192) xm[pix * CIN + t] = acc[p];
        else         z[pix * CIN + (t - 192)] = acc[p];
    }
}

// K2: depthwise 3x3 conv, pad 1
__global__ __launch_bounds__(256) void k_conv(
    const float* __restrict__ xm, const float* __restrict__ cw,
    const float* __restrict__ cb, float* __restrict__ xcv)
{
    int e = blockIdx.x * 256 + threadIdx.x;
    if (e >= NPIX * CIN) return;
    int c = e % CIN;
    int pix = e / CIN;
    int w = pix % HW;
    int rest = pix / HW;
    int h = rest % HW;
    int b = rest / HW;
    float acc = cb[c];
#pragma unroll
    for (int ky = 0; ky < 3; ++ky) {
        int hh = h + ky - 1;
        if (hh < 0 || hh >= HW) continue;
#pragma unroll
        for (int kx = 0; kx < 3; ++kx) {
            int ww = w + kx - 1;
            if (ww < 0 || ww >= HW) continue;
            acc = fmaf(xm[((b * HW + hh) * HW + ww) * CIN + c],
                       cw[(ky * 3 + kx) * CIN + c], acc);
        }
    }
    xcv[e] = acc;
}

// K3a: x_dbl = xcv @ W_xproj -> dtr(6)/B(16)/C(16).
// 24 pixels/block; thread = (j in 0..39, pixel-quad pq in 0..5); per k:
// 1 weight load + 1 ds_read_b128 + 4 FMA.
__global__ __launch_bounds__(256) void k_xproj(
    const float* __restrict__ xcv, const float* __restrict__ W_xproj,
    float* __restrict__ dtr, float* __restrict__ Bp, float* __restrict__ Cp)
{
    __shared__ __align__(16) float xs[192][28];  // pad 28: [k][4*pq] 16B-aligned
    const int p0 = blockIdx.x * 24;
    const int t = threadIdx.x;
    for (int e = t; e < 24 * 192; e += 256) {
        int p = e / 192, kk = e % 192;
        int pix = p0 + p;
        xs[kk][p] = (pix < NPIX) ? xcv[pix * CIN + kk] : 0.f;
    }
    __syncthreads();
    const int j  = t % 40;
    const int pq = t / 40;               // 0..6; 6 is idle
    if (pq >= 6) return;
    const int jc = (j < 38) ? j : 37;
    float a0 = 0.f, a1 = 0.f, a2 = 0.f, a3 = 0.f;
    for (int k = 0; k < 192; ++k) {
        float w = W_xproj[k * 38 + jc];
        float4 xv = *(const float4*)&xs[k][pq * 4];
        a0 = fmaf(xv.x, w, a0); a1 = fmaf(xv.y, w, a1);
        a2 = fmaf(xv.z, w, a2); a3 = fmaf(xv.w, w, a3);
    }
    if (j < 38) {
        float r[4] = {a0, a1, a2, a3};
#pragma unroll
        for (int q = 0; q < 4; ++q) {
            int pix = p0 + pq * 4 + q;
            if (pix >= NPIX) continue;
            if (j < 6)       dtr[pix * 6 + j] = r[q];
            else if (j < 22) Bp[pix * NST + (j - 6)] = r[q];
            else             Cp[pix * NST + (j - 22)] = r[q];
        }
    }
}

// K3b: dt = softplus(dtr @ W_dt + b_dt)
__global__ __launch_bounds__(256) void k_dt(
    const float* __restrict__ dtr, const float* __restrict__ W_dt,
    const float* __restrict__ b_dt, float* __restrict__ dtp)
{
    int idx = blockIdx.x * 256 + threadIdx.x;
    if (idx >= NPIX * CIN) return;
    int c = idx % CIN;
    int pix = idx / CIN;
    float v = b_dt[c];
#pragma unroll
    for (int r = 0; r < 6; ++r) v = fmaf(dtr[pix * 6 + r], W_dt[r * CIN + c], v);
    dtp[idx] = softplusf(v);
}

// K4b pass1 (templated on CHUNK): lane = channel, 16 states in registers.
template<int CHUNK>
__global__ __launch_bounds__(192) void k_scan_p1(
    const float* __restrict__ xcv, const float* __restrict__ dtp,
    const float* __restrict__ Bp, const float* __restrict__ A_log,
    float* __restrict__ Pbuf, float* __restrict__ qbuf)
{
    constexpr int CPR = HW / CHUNK;    // chunks per row
    __shared__ __align__(16) float Bs[CHUNK * NST];
    const int g = blockIdx.y;          // 0..7
    const int k = blockIdx.x;          // chunk id
    const int c = threadIdx.x;         // 0..191
    const int d = g >> 1, b = g & 1;
    int si, sj, off;
    dir_geom(d, b, si, sj, off);
    const int base = off + (k / CPR) * si + ((k % CPR) * CHUNK) * sj;

    for (int e = c; e < CHUNK * NST; e += 192) {
        int jj = e >> 4, n = e & 15;
        Bs[e] = Bp[(base + jj * sj) * NST + n];
    }

    const float LOG2E = 1.4426950408889634f;
    float a2[NST];
    {
        const float4* Ar = (const float4*)(A_log + c * NST);
#pragma unroll
        for (int q = 0; q < 4; ++q) {
            float4 v = Ar[q];
            a2[q*4+0] = -expf(v.x) * LOG2E;
            a2[q*4+1] = -expf(v.y) * LOG2E;
            a2[q*4+2] = -expf(v.z) * LOG2E;
            a2[q*4+3] = -expf(v.w) * LOG2E;
        }
    }
    __syncthreads();

    float h[NST], P[NST];
#pragma unroll
    for (int n = 0; n < NST; ++n) { h[n] = 0.f; P[n] = 1.f; }

    float dt_v = dtp[base * CIN + c];
    float x_v  = xcv[base * CIN + c];
    for (int jj = 0; jj < CHUNK; ++jj) {
        float dt_c = dt_v, x_c = x_v;
        int jn = (jj + 1 < CHUNK) ? jj + 1 : jj;
        int pixn = base + jn * sj;
        dt_v = dtp[pixn * CIN + c];
        x_v  = xcv[pixn * CIN + c];
        float dtx = dt_c * x_c;
        float Bv[NST];
        {
            const float4* Brow = (const float4*)(Bs + jj * NST);
#pragma unroll
            for (int q = 0; q < 4; ++q) {
                float4 t = Brow[q];
                Bv[q*4+0]=t.x; Bv[q*4+1]=t.y; Bv[q*4+2]=t.z; Bv[q*4+3]=t.w;
            }
        }
#pragma unroll
        for (int n = 0; n < NST; ++n) {
            float dA = exp2f(dt_c * a2[n]);
            h[n] = fmaf(dA, h[n], dtx * Bv[n]);
            P[n] *= dA;
        }
    }
    float4* Pd = (float4*)(Pbuf + ((size_t)(k * 8 + g) * CIN + c) * NST);
    float4* qd = (float4*)(qbuf + ((size_t)(k * 8 + g) * CIN + c) * NST);
#pragma unroll
    for (int q = 0; q < 4; ++q) {
        Pd[q] = make_float4(P[q*4], P[q*4+1], P[q*4+2], P[q*4+3]);
        qd[q] = make_float4(h[q*4], h[q*4+1], h[q*4+2], h[q*4+3]);
    }
}

// K4c: sequential chunk combine, 8-deep load pipeline; overwrites qbuf[k]
// with h_start of chunk k.
__global__ __launch_bounds__(256) void k_scan_fix(
    const float* __restrict__ Pbuf, float* __restrict__ qbuf, int nch)
{
    const int g = blockIdx.y;
    const int lo = blockIdx.x * 256 + threadIdx.x;   // 0..3071 = c*16+n
    const size_t stride = (size_t)8 * CIN * NST;     // 24576 per chunk
    size_t idx  = (size_t)g * CIN * NST + lo;
    size_t pidx = idx;
    float Pr[8], qr[8];
#pragma unroll
    for (int i = 0; i < 8; ++i) { Pr[i] = Pbuf[pidx]; qr[i] = qbuf[pidx]; pidx += stride; }
    float h = 0.f;
    for (int k = 0; k < nch; k += 8) {
        float Pn[8], qn[8];
        if (k + 8 < nch) {
#pragma unroll
            for (int i = 0; i < 8; ++i) {
                Pn[i] = Pbuf[pidx + (size_t)i * stride];
                qn[i] = qbuf[pidx + (size_t)i * stride];
            }
        } else {
#pragma unroll
            for (int i = 0; i < 8; ++i) { Pn[i] = 0.f; qn[i] = 0.f; }
        }
#pragma unroll
        for (int i = 0; i < 8; ++i) {
            qbuf[idx] = h;                 // h_start for chunk k+i
            h = fmaf(Pr[i], h, qr[i]);
            idx += stride;
        }
#pragma unroll
        for (int i = 0; i < 8; ++i) { Pr[i] = Pn[i]; qr[i] = qn[i]; }
        pidx += (size_t)8 * stride;
    }
}

// K4d pass2 (templated): rerun chunk from h_start; y goes to per-direction
// slab Y4[d] at SEQUENCE position l = k*CHUNK + jj via plain coalesced store
// (each (d,b,l,c) written exactly once -> no atomics, no zero-init).
template<int CHUNK>
__global__ __launch_bounds__(192) void k_scan_p2(
    const float* __restrict__ xcv, const float* __restrict__ dtp,
    const float* __restrict__ Bp, const float* __restrict__ Cp,
    const float* __restrict__ A_log, const float* __restrict__ D_skip,
    const float* __restrict__ qbuf, float* __restrict__ Y4)
{
    constexpr int CPR = HW / CHUNK;
    __shared__ __align__(16) float Bs[CHUNK * NST];
    __shared__ __align__(16) float Cs[CHUNK * NST];
    const int g = blockIdx.y;
    const int k = blockIdx.x;
    const int c = threadIdx.x;
    const int d = g >> 1, b = g & 1;
    int si, sj, off;
    dir_geom(d, b, si, sj, off);
    const int base = off + (k / CPR) * si + ((k % CPR) * CHUNK) * sj;

    for (int e = c; e < CHUNK * NST; e += 192) {
        int jj = e >> 4, n = e & 15;
        int pa = (base + jj * sj) * NST + n;
        Bs[e] = Bp[pa];
        Cs[e] = Cp[pa];
    }

    const float LOG2E = 1.4426950408889634f;
    float a2[NST];
    {
        const float4* Ar = (const float4*)(A_log + c * NST);
#pragma unroll
        for (int q = 0; q < 4; ++q) {
            float4 v = Ar[q];
            a2[q*4+0] = -expf(v.x) * LOG2E;
            a2[q*4+1] = -expf(v.y) * LOG2E;
            a2[q*4+2] = -expf(v.z) * LOG2E;
            a2[q*4+3] = -expf(v.w) * LOG2E;
        }
    }
    const float Dc = D_skip[c];

    float h[NST];
    {
        const float4* qd = (const float4*)(qbuf + ((size_t)(k * 8 + g) * CIN + c) * NST);
#pragma unroll
        for (int q = 0; q < 4; ++q) {
            float4 v = qd[q];
            h[q*4+0]=v.x; h[q*4+1]=v.y; h[q*4+2]=v.z; h[q*4+3]=v.w;
        }
    }
    __syncthreads();

    float* yo = Y4 + ((size_t)d * NPIX + (size_t)b * LVAL + (size_t)k * CHUNK) * CIN;

    float dt_v = dtp[base * CIN + c];
    float x_v  = xcv[base * CIN + c];
    for (int jj = 0; jj < CHUNK; ++jj) {
        float dt_c = dt_v, x_c = x_v;
        int jn = (jj + 1 < CHUNK) ? jj + 1 : jj;
        int pixn = base + jn * sj;
        dt_v = dtp[pixn * CIN + c];
        x_v  = xcv[pixn * CIN + c];
        float dtx = dt_c * x_c;
        float Bv[NST], Cv[NST];
        {
            const float4* Brow = (const float4*)(Bs + jj * NST);
            const float4* Crow = (const float4*)(Cs + jj * NST);
#pragma unroll
            for (int q = 0; q < 4; ++q) {
                float4 t = Brow[q], u = Crow[q];
                Bv[q*4+0]=t.x; Bv[q*4+1]=t.y; Bv[q*4+2]=t.z; Bv[q*4+3]=t.w;
                Cv[q*4+0]=u.x; Cv[q*4+1]=u.y; Cv[q*4+2]=u.z; Cv[q*4+3]=u.w;
            }
        }
        float yc0 = Dc * x_c, yc1 = 0.f;
#pragma unroll
        for (int n = 0; n < NST; n += 2) {
            float dA0 = exp2f(dt_c * a2[n]);
            float dA1 = exp2f(dt_c * a2[n+1]);
            h[n]   = fmaf(dA0, h[n],   dtx * Bv[n]);
            h[n+1] = fmaf(dA1, h[n+1], dtx * Bv[n+1]);
            yc0 = fmaf(h[n],   Cv[n],   yc0);
            yc1 = fmaf(h[n+1], Cv[n+1], yc1);
        }
        yo[jj * CIN + c] = yc0 + yc1;
    }
}

// K5a: yv = silu(z) * (Y4[0]+Y4[1]+Y4[2]+Y4[3])
__global__ __launch_bounds__(256) void k_gate(
    const float* __restrict__ Y4, const float* __restrict__ z,
    float* __restrict__ yv)
{
    int idx = blockIdx.x * 256 + threadIdx.x;
    if (idx >= NPIX * CIN) return;
    const size_t NP = (size_t)NPIX * CIN;
    float s = Y4[idx] + Y4[idx + NP] + Y4[idx + 2 * NP] + Y4[idx + 3 * NP];
    float zz = z[idx];
    float sig = 1.f / (1.f + expf(-zz));
    yv[idx] = zz * sig * s;
}

// K5b: out = yv @ W_out. 16 pixels/block, LDS-broadcast yv, acc[8]/thread.
__global__ __launch_bounds__(192) void k_outproj(
    const float* __restrict__ yv, const float* __restrict__ W_out,
    float* __restrict__ out)
{
    __shared__ __align__(16) float xs[192][20];
    const int p0 = blockIdx.x * 16;
    const int t = threadIdx.x;
    for (int e = t; e < 16 * 192; e += 192) {
        int p = e / 192, kk = e % 192;
        xs[kk][p] = yv[(p0 + p) * CIN + kk];
    }
    __syncthreads();
    const int j  = t % 96;
    const int ph = t / 96;          // 0..1 -> pixels ph*8 .. ph*8+7
    float acc[8];
#pragma unroll
    for (int p = 0; p < 8; ++p) acc[p] = 0.f;
    for (int k = 0; k < 192; ++k) {
        float w = W_out[k * 96 + j];
        float4 x0 = *(const float4*)&xs[k][ph * 8];
        float4 x1 = *(const float4*)&xs[k][ph * 8 + 4];
        acc[0] = fmaf(x0.x, w, acc[0]); acc[1] = fmaf(x0.y, w, acc[1]);
        acc[2] = fmaf(x0.z, w, acc[2]); acc[3] = fmaf(x0.w, w, acc[3]);
        acc[4] = fmaf(x1.x, w, acc[4]); acc[5] = fmaf(x1.y, w, acc[5]);
        acc[6] = fmaf(x1.z, w, acc[6]); acc[7] = fmaf(x1.w, w, acc[7]);
    }
#pragma unroll
    for (int p = 0; p < 8; ++p)
        out[(p0 + ph * 8 + p) * 96 + j] = acc[p];
}

template<int CHUNK>
static void launch_scan(const float* xcv, const float* dtp, const float* Bp,
                        const float* Cp, const float* A_log, const float* D_skip,
                        float* Pbuf, float* qbuf, float* Y4, hipStream_t stream)
{
    const int nch = LVAL / CHUNK;
    k_scan_p1<CHUNK><<<dim3(nch, 8), 192, 0, stream>>>(xcv, dtp, Bp, A_log, Pbuf, qbuf);
    k_scan_fix<<<dim3(12, 8), 256, 0, stream>>>(Pbuf, qbuf, nch);
    k_scan_p2<CHUNK><<<dim3(nch, 8), 192, 0, stream>>>(xcv, dtp, Bp, Cp, A_log, D_skip, qbuf, Y4);
}

extern "C" void kernel_launch(void* const* d_in, const int* in_sizes, int n_in,
                              void* d_out, int out_size, void* d_ws, size_t ws_size,
                              hipStream_t stream) {
    const float* x      = (const float*)d_in[0];
    const float* W_in   = (const float*)d_in[1];
    const float* conv_w = (const float*)d_in[2];
    const float* conv_b = (const float*)d_in[3];
    const float* W_xproj= (const float*)d_in[4];
    const float* W_dt   = (const float*)d_in[5];
    const float* b_dt   = (const float*)d_in[6];
    const float* A_log  = (const float*)d_in[7];
    const float* D_skip = (const float*)d_in[8];
    const float* W_out  = (const float*)d_in[9];
    float* out = (float*)d_out;

    float* ws  = (float*)d_ws;
    float* xm  = ws;                        // [NPIX*CIN]
    float* z   = xm  + NPIX * CIN;          // [NPIX*CIN]
    float* xcv = z   + NPIX * CIN;          // [NPIX*CIN] ; reused as yv after p2
    float* dtp = xcv + NPIX * CIN;          // [NPIX*CIN]
    float* dtr = dtp + NPIX * CIN;          // [NPIX*6]
    float* Bp  = dtr + NPIX * 6;            // [NPIX*NST]
    float* Cp  = Bp  + NPIX * NST;          // [NPIX*NST]
    float* Y4  = Cp  + NPIX * NST;          // [4*NPIX*CIN] per-direction y slabs
    float* Pbuf= Y4  + (size_t)4 * NPIX * CIN;   // [nch*8*CIN*NST]
    // base = 9,872,128 floats (39.5 MB); carry bufs = 2*nch*24576 floats

    const size_t base_fl = 9872128;
    const size_t ws_fl = ws_size / 4;
    // pick smallest CHUNK (most parallelism) whose carry buffers fit
    int chunk;
    if      (ws_fl >= base_fl + (size_t)2 * 224 * 24576) chunk = 14;  // 83.5 MB
    else if (ws_fl >= base_fl + (size_t)2 * 112 * 24576) chunk = 28;  // 61.5 MB
    else                                                 chunk = 56;  // 50.5 MB
    float* qbuf = Pbuf + (size_t)(LVAL / chunk) * 8 * CIN * NST;

    k_inproj  <<<NPIX / 16, 384, 0, stream>>>(x, W_in, xm, z);
    k_conv    <<<(NPIX * CIN) / 256, 256, 0, stream>>>(xm, conv_w, conv_b, xcv);
    k_xproj   <<<(NPIX + 23) / 24, 256, 0, stream>>>(xcv, W_xproj, dtr, Bp, Cp);
    k_dt      <<<(NPIX * CIN) / 256, 256, 0, stream>>>(dtr, W_dt, b_dt, dtp);
    if      (chunk == 14) launch_scan<14>(xcv, dtp, Bp, Cp, A_log, D_skip, Pbuf, qbuf, Y4, stream);
    else if (chunk == 28) launch_scan<28>(xcv, dtp, Bp, Cp, A_log, D_skip, Pbuf, qbuf, Y4, stream);
    else                  launch_scan<56>(xcv, dtp, Bp, Cp, A_log, D_skip, Pbuf, qbuf, Y4, stream);
    k_gate    <<<(NPIX * CIN) / 256, 256, 0, stream>>>(Y4, z, xcv);    // yv -> xcv
    k_outproj <<<NPIX / 16, 192, 0, stream>>>(xcv, W_out, out);
}